// Round 7
// baseline (2657.911 us; speedup 1.0000x reference)
//
#include <hip/hip_runtime.h>
#include <hip/hip_bf16.h>
#include <stdint.h>

#define BB 32
#define NN 128
#define TT 16
#define FN 16
#define FE 8
#define FG 8
#define FH 16
#define HH 128
#define DEC 64

// ws layout (floats):
// base_node @0        [524288]
// We        @524288   [1024]
// mg        @525312   [4096]
// m1p       @529408   [524288]
// m2        @1053696  [524288]
// o1        @1577984  [524288]
// hidden    @2102272  [524288]
// eg16      @2626560  [2097152]  (4096*128 rows x 16B bf16x8)
// jl (int)  @4723712  [524288]
// cnt (int) @5248000  [4096]
// end 5252096 floats = 21.0 MB

__global__ __launch_bounds__(HH) void prep1(const float* __restrict__ node,
                                            const float* __restrict__ Wn,
                                            float* __restrict__ base_node,
                                            float* __restrict__ hidden) {
    int row = blockIdx.x;
    int h = threadIdx.x;
    float acc = 0.f;
#pragma unroll
    for (int f = 0; f < FN; ++f)
        acc += node[row * FN + f] * Wn[f * HH + h];
    base_node[row * HH + h] = acc;
    hidden[row * HH + h] = 0.f;
}

// grid = BB + FE blocks: 0..31 compute mg[b][h]; 32..39 compute We[f][h].
// unroll 16 keeps 16 cold-HBM loads in flight (latency-bound otherwise).
__global__ __launch_bounds__(HH) void prep2(const float* __restrict__ graph,
                                            const float* __restrict__ Wg,
                                            const float* __restrict__ Wmg,
                                            const float* __restrict__ Wee,
                                            const float* __restrict__ Wme,
                                            float* __restrict__ mg,
                                            float* __restrict__ We) {
    int h = threadIdx.x;
    if (blockIdx.x < BB) {
        int b = blockIdx.x;
        __shared__ float gf[HH];
        float acc = 0.f;
#pragma unroll
        for (int f = 0; f < FG; ++f) acc += graph[b * FG + f] * Wg[f * HH + h];
        gf[h] = acc;
        __syncthreads();
        float a2 = 0.f;
#pragma unroll 16
        for (int k = 0; k < HH; ++k) a2 += gf[k] * Wmg[k * HH + h];
        mg[b * HH + h] = a2;
    } else {
        int f = blockIdx.x - BB;
        float acc = 0.f;
#pragma unroll 16
        for (int k = 0; k < HH; ++k) acc += Wee[f * HH + k] * Wme[k * HH + h];
        We[f * HH + h] = acc;
    }
}

__device__ __forceinline__ uint32_t bf16rne(float v) {
    uint32_t b = __float_as_uint(v);
    return (b + 0x7fffu + ((b >> 16) & 1u)) >> 16;
}

// Compact valid senders into bf16-packed rows; pad count to multiple of 8
// with duplicates of the first valid entry (max is idempotent).
__global__ __launch_bounds__(HH) void prep3(const float* __restrict__ edge,
                                            const int* __restrict__ adj,
                                            uint4* __restrict__ eg16,
                                            int* __restrict__ jl,
                                            int* __restrict__ cnt) {
    int bi = blockIdx.x;
    int j = threadIdx.x;
    __shared__ int w0cnt, totc, j0s;
    bool valid = adj[(size_t)bi * NN + j] > 0;
    unsigned long long mask = __ballot(valid);
    int lane = j & 63;
    int wave = j >> 6;
    int prefix = __popcll(mask & ((1ull << lane) - 1ull));
    int wcount = __popcll(mask);
    if (wave == 0 && lane == 0) w0cnt = wcount;
    __syncthreads();
    int base = (wave == 1) ? w0cnt : 0;
    if (wave == 1 && lane == 0) totc = w0cnt + wcount;
    int pos = base + prefix;
    if (valid && pos == 0) j0s = j;
    __syncthreads();
    int c = totc;
    int cpad = (c + 7) & ~7;
    if (j == 0) cnt[bi] = cpad;

    if (valid) {
        jl[bi * NN + pos] = j;
        const float* src = edge + ((size_t)bi * NN + j) * FE;
        uint4 r;
        r.x = bf16rne(src[0]) | (bf16rne(src[1]) << 16);
        r.y = bf16rne(src[2]) | (bf16rne(src[3]) << 16);
        r.z = bf16rne(src[4]) | (bf16rne(src[5]) << 16);
        r.w = bf16rne(src[6]) | (bf16rne(src[7]) << 16);
        eg16[(size_t)bi * NN + pos] = r;
    }
    if (c > 0 && j >= c && j < cpad) {
        int j0 = j0s;
        jl[bi * NN + j] = j0;
        const float* src = edge + ((size_t)bi * NN + j0) * FE;
        uint4 r;
        r.x = bf16rne(src[0]) | (bf16rne(src[1]) << 16);
        r.y = bf16rne(src[2]) | (bf16rne(src[3]) << 16);
        r.z = bf16rne(src[4]) | (bf16rne(src[5]) << 16);
        r.w = bf16rne(src[6]) | (bf16rne(src[7]) << 16);
        eg16[(size_t)bi * NN + j] = r;
    }
}

// K1: 768 blocks = 256 tiles (16 rows) x 3 matrices, 64 threads (1 wave).
// zT[k][row] transposed LDS tile: one ds_read_b128 feeds 4 rows.
// Thread = 4 rows x 8 cols (32 acc); per k: 1 LDS b128 + 2 weight b128 + 32 FMA.
// 4-slot register pipeline, 3-deep prefetch (static slot indices).
__global__ __launch_bounds__(64) void k1_gemm(
    const float* __restrict__ base_node, const float* __restrict__ hidden,
    const float* __restrict__ hints, const float* __restrict__ Wh,
    const float* __restrict__ Wm1, const float* __restrict__ Wm2,
    const float* __restrict__ Wo1, const float* __restrict__ mg,
    float* __restrict__ m1p, float* __restrict__ m2, float* __restrict__ o1,
    int t) {
    __shared__ float zT[256][20];       // pitch 20 floats: 16B-aligned rows
    const int tid = threadIdx.x;        // 0..63
    const int rowg = tid >> 4;          // 0..3 -> rows rowg*4..+3
    const int c0 = (tid & 15) * 8;      // col group of 8
    const int bid = blockIdx.x;
    const int xcd = bid & 7;
    const int idx = bid >> 3;           // 0..95
    const int tile = xcd * 32 + (idx & 31);
    const int mat = idx >> 5;           // 0,1,2
    const int row0 = tile * 16;

    // ---- stage zT: thread handles h = tid and tid+64 ----
#pragma unroll
    for (int e = 0; e < 2; ++e) {
        const int h = tid + e * 64;
        float whr[FH];
        if (t > 0) {
#pragma unroll
            for (int f = 0; f < FH; ++f) whr[f] = Wh[f * HH + h];
        }
        float nv[16];
#pragma unroll
        for (int r = 0; r < 16; ++r) {
            int row = row0 + r;
            float nf = base_node[row * HH + h];
            if (t > 0) {
                const float* hr = hints + ((size_t)(t - 1) * BB * NN + row) * FH;
#pragma unroll
                for (int f = 0; f < FH; ++f) nf = fmaf(hr[f], whr[f], nf);
            }
            nv[r] = nf;
        }
#pragma unroll
        for (int w = 0; w < 4; ++w)
            *(float4*)&zT[h][w * 4] =
                make_float4(nv[w * 4], nv[w * 4 + 1], nv[w * 4 + 2], nv[w * 4 + 3]);
#pragma unroll
        for (int r = 0; r < 16; ++r) nv[r] = hidden[(row0 + r) * HH + h];
#pragma unroll
        for (int w = 0; w < 4; ++w)
            *(float4*)&zT[HH + h][w * 4] =
                make_float4(nv[w * 4], nv[w * 4 + 1], nv[w * 4 + 2], nv[w * 4 + 3]);
    }
    __syncthreads();

    const float* __restrict__ W = (mat == 0) ? Wm1 : (mat == 1) ? Wm2 : Wo1;

    float acc[4][8];
#pragma unroll
    for (int r = 0; r < 4; ++r)
#pragma unroll
        for (int c = 0; c < 8; ++c) acc[r][c] = 0.f;

    float4 zb[4], w0b[4], w1b[4];

#define LOADK(S, K)                                                        \
    {                                                                      \
        zb[S] = *(const float4*)&zT[K][rowg * 4];                          \
        const float* wp = W + (K) * HH + c0;                               \
        w0b[S] = *(const float4*)wp;                                       \
        w1b[S] = *(const float4*)(wp + 4);                                 \
    }
#define COMPK(S)                                                           \
    {                                                                      \
        float zr[4] = {zb[S].x, zb[S].y, zb[S].z, zb[S].w};                \
        float wv[8] = {w0b[S].x, w0b[S].y, w0b[S].z, w0b[S].w,             \
                       w1b[S].x, w1b[S].y, w1b[S].z, w1b[S].w};            \
        _Pragma("unroll") for (int r = 0; r < 4; ++r)                      \
            _Pragma("unroll") for (int c = 0; c < 8; ++c)                  \
                acc[r][c] = fmaf(zr[r], wv[c], acc[r][c]);                 \
    }

    LOADK(0, 0) LOADK(1, 1) LOADK(2, 2)
    for (int k4 = 0; k4 < 64; ++k4) {
        const int k = k4 * 4;
        const int p0 = (k + 3 < 256) ? k + 3 : 0;
        const int p1 = (k + 4 < 256) ? k + 4 : 0;
        const int p2 = (k + 5 < 256) ? k + 5 : 0;
        const int p3 = (k + 6 < 256) ? k + 6 : 0;
        LOADK(3, p0) COMPK(0)
        LOADK(0, p1) COMPK(1)
        LOADK(1, p2) COMPK(2)
        LOADK(2, p3) COMPK(3)
    }
#undef LOADK
#undef COMPK

    const int b = row0 >> 7;
    if (mat == 0) {
        float4 mg0 = *(const float4*)&mg[b * HH + c0];
        float4 mg1 = *(const float4*)&mg[b * HH + c0 + 4];
#pragma unroll
        for (int r = 0; r < 4; ++r) {
            int row = row0 + rowg * 4 + r;
            float4 v0 = make_float4(acc[r][0] + mg0.x, acc[r][1] + mg0.y,
                                    acc[r][2] + mg0.z, acc[r][3] + mg0.w);
            float4 v1 = make_float4(acc[r][4] + mg1.x, acc[r][5] + mg1.y,
                                    acc[r][6] + mg1.z, acc[r][7] + mg1.w);
            *(float4*)&m1p[row * HH + c0] = v0;
            *(float4*)&m1p[row * HH + c0 + 4] = v1;
        }
    } else {
        float* __restrict__ outp = (mat == 1) ? m2 : o1;
#pragma unroll
        for (int r = 0; r < 4; ++r) {
            int row = row0 + rowg * 4 + r;
            float4 v0 = make_float4(acc[r][0], acc[r][1], acc[r][2], acc[r][3]);
            float4 v1 = make_float4(acc[r][4], acc[r][5], acc[r][6], acc[r][7]);
            *(float4*)&outp[row * HH + c0] = v0;
            *(float4*)&outp[row * HH + c0 + 4] = v1;
        }
    }
}

// K2: 128 threads (h), serial compacted j-loop, unroll-8 batches, bf16 eg rows.
// XCD-swizzled so blocks of the same batch share an XCD-L2 with k1's writes.
__global__ __launch_bounds__(HH) void k2_max(
    const uint4* __restrict__ eg16, const int* __restrict__ jl,
    const int* __restrict__ cnt, const float* __restrict__ We,
    const float* __restrict__ m1p, const float* __restrict__ m2,
    const float* __restrict__ o1, const float* __restrict__ Wo2,
    const float* __restrict__ Wdn, const float* __restrict__ Wde,
    float* __restrict__ hidden, float* __restrict__ out, int t, int last) {
    __shared__ float agg_lds[HH];
    __shared__ float hnew_lds[HH];
    const int h = threadIdx.x;
    const int bid = blockIdx.x;
    const int bi = (bid & 7) * 512 + (bid >> 3);
    const int b = bi >> 7;

    const float we0 = We[0 * HH + h], we1 = We[1 * HH + h];
    const float we2 = We[2 * HH + h], we3 = We[3 * HH + h];
    const float we4 = We[4 * HH + h], we5 = We[5 * HH + h];
    const float we6 = We[6 * HH + h], we7 = We[7 * HH + h];

    const uint4* __restrict__ egp = eg16 + (size_t)bi * NN;
    const int* __restrict__ jlb = jl + bi * NN;
    const float* __restrict__ m2b = m2 + (size_t)b * NN * HH;
    const int cp = cnt[bi];
    const float m1v = m1p[bi * HH + h];
    const float o1v = o1[bi * HH + h];

    float M = -3e38f;
    const int nch = cp >> 3;
    for (int ch = 0; ch < nch; ++ch) {
        const int k0 = ch * 8;
        uint4 raw[8];
        int jj[8];
        float mv[8];
#pragma unroll
        for (int s = 0; s < 8; ++s) raw[s] = egp[k0 + s];
#pragma unroll
        for (int s = 0; s < 8; ++s) jj[s] = jlb[k0 + s];
#pragma unroll
        for (int s = 0; s < 8; ++s) mv[s] = m2b[jj[s] * HH + h];
#pragma unroll
        for (int s = 0; s < 8; ++s) {
            uint32_t x = raw[s].x, y = raw[s].y, z = raw[s].z, w = raw[s].w;
            float e = __uint_as_float(x << 16) * we0;
            e = fmaf(__uint_as_float(x & 0xffff0000u), we1, e);
            e = fmaf(__uint_as_float(y << 16), we2, e);
            e = fmaf(__uint_as_float(y & 0xffff0000u), we3, e);
            e = fmaf(__uint_as_float(z << 16), we4, e);
            e = fmaf(__uint_as_float(z & 0xffff0000u), we5, e);
            e = fmaf(__uint_as_float(w << 16), we6, e);
            e = fmaf(__uint_as_float(w & 0xffff0000u), we7, e);
            M = fmaxf(M, e + mv[s]);
        }
    }
    float agg = (cp > 0) ? fmaxf(m1v + M, 0.f) : -1e9f;
    agg_lds[h] = agg;
    __syncthreads();

    float acc = o1v;
    const float4* a4 = (const float4*)agg_lds;
#pragma unroll 8
    for (int kk = 0; kk < 32; ++kk) {
        float4 a = a4[kk];
        acc = fmaf(a.x, Wo2[(kk * 4 + 0) * HH + h], acc);
        acc = fmaf(a.y, Wo2[(kk * 4 + 1) * HH + h], acc);
        acc = fmaf(a.z, Wo2[(kk * 4 + 2) * HH + h], acc);
        acc = fmaf(a.w, Wo2[(kk * 4 + 3) * HH + h], acc);
    }
    float hv = fmaxf(acc, 0.f);
    hidden[bi * HH + h] = hv;

    if (last) {
        hnew_lds[h] = hv;
        __syncthreads();
        if (h < DEC) {
            float a = 0.f, e2 = 0.f;
            const float4* h4p = (const float4*)hnew_lds;
#pragma unroll 8
            for (int kk = 0; kk < 32; ++kk) {
                float4 hv4 = h4p[kk];
                float4 av4 = a4[kk];
                a = fmaf(hv4.x, Wdn[(kk * 4 + 0) * DEC + h], a);
                a = fmaf(hv4.y, Wdn[(kk * 4 + 1) * DEC + h], a);
                a = fmaf(hv4.z, Wdn[(kk * 4 + 2) * DEC + h], a);
                a = fmaf(hv4.w, Wdn[(kk * 4 + 3) * DEC + h], a);
                e2 = fmaf(av4.x, Wde[(kk * 4 + 0) * DEC + h], e2);
                e2 = fmaf(av4.y, Wde[(kk * 4 + 1) * DEC + h], e2);
                e2 = fmaf(av4.z, Wde[(kk * 4 + 2) * DEC + h], e2);
                e2 = fmaf(av4.w, Wde[(kk * 4 + 3) * DEC + h], e2);
            }
            out[(((size_t)t * BB + b) * NN + (bi & 127)) * DEC + h] = a + e2;
        }
    }
}

extern "C" void kernel_launch(void* const* d_in, const int* in_sizes, int n_in,
                              void* d_out, int out_size, void* d_ws, size_t ws_size,
                              hipStream_t stream) {
    const float* node = (const float*)d_in[0];
    const float* edge = (const float*)d_in[1];
    const float* graph = (const float*)d_in[2];
    const float* hints = (const float*)d_in[3];
    const int* adj = (const int*)d_in[4];
    const float* Wn = (const float*)d_in[5];
    const float* Wh = (const float*)d_in[6];
    const float* Wee = (const float*)d_in[7];
    const float* Wg = (const float*)d_in[8];
    const float* Wm1 = (const float*)d_in[9];
    const float* Wm2 = (const float*)d_in[10];
    const float* Wme = (const float*)d_in[11];
    const float* Wmg = (const float*)d_in[12];
    const float* Wo1 = (const float*)d_in[13];
    const float* Wo2 = (const float*)d_in[14];
    const float* Wdn = (const float*)d_in[15];
    const float* Wde = (const float*)d_in[16];

    float* ws = (float*)d_ws;
    float* base_node = ws;
    float* We = ws + 524288;
    float* mg = ws + 525312;
    float* m1p = ws + 529408;
    float* m2 = ws + 1053696;
    float* o1 = ws + 1577984;
    float* hidden = ws + 2102272;
    uint4* eg16 = (uint4*)(ws + 2626560);
    int* jl = (int*)(ws + 4723712);
    int* cnt = (int*)(ws + 5248000);
    float* out = (float*)d_out;

    prep1<<<BB * NN, HH, 0, stream>>>(node, Wn, base_node, hidden);
    prep2<<<BB + FE, HH, 0, stream>>>(graph, Wg, Wmg, Wee, Wme, mg, We);
    prep3<<<BB * NN, HH, 0, stream>>>(edge, adj, eg16, jl, cnt);

    for (int t = 0; t < TT; ++t) {
        for (int ms = 0; ms < 3; ++ms) {
            k1_gemm<<<768, 64, 0, stream>>>(base_node, hidden, hints, Wh,
                                            Wm1, Wm2, Wo1, mg,
                                            m1p, m2, o1, t);
            k2_max<<<BB * NN, HH, 0, stream>>>(eg16, jl, cnt, We, m1p, m2, o1,
                                               Wo2, Wdn, Wde, hidden, out, t,
                                               ms == 2 ? 1 : 0);
        }
    }
}